// Round 11
// baseline (207.146 us; speedup 1.0000x reference)
//
#include <hip/hip_runtime.h>
#include <hip/hip_bf16.h>
#include <math.h>

typedef float f32x4 __attribute__((ext_vector_type(4)));
typedef __bf16 bf16x8 __attribute__((ext_vector_type(8)));
typedef unsigned short u16;
typedef u16 u16x8 __attribute__((ext_vector_type(8)));
typedef u16 u16x4 __attribute__((ext_vector_type(4)));
typedef unsigned ui32x4 __attribute__((ext_vector_type(4)));

// round-to-nearest-even fp32 -> bf16
__device__ __forceinline__ u16 f2bf(float f) {
    unsigned u = __builtin_bit_cast(unsigned, f);
    u = (u + 0x7fffu + ((u >> 16) & 1u)) >> 16;
    return (u16)u;
}
// pack two fp32 -> two bf16 (RNE) in ONE VALU op (no builtin on gfx950 - inline asm)
__device__ __forceinline__ unsigned cvtpk(float a, float b) {
    unsigned r;
    asm("v_cvt_pk_bf16_f32 %0, %1, %2" : "=v"(r) : "v"(a), "v"(b));
    return r;
}

#if __has_builtin(__builtin_amdgcn_exp2f)
#define EXP2(x) __builtin_amdgcn_exp2f(x)
#else
#define EXP2(x) exp2f(x)
#endif

// async global->LDS 16B/lane: LDS dest = wave-uniform base + lane*16
__device__ __forceinline__ void gload16(const u16* g, u16* l) {
    __builtin_amdgcn_global_load_lds(
        (const __attribute__((address_space(1))) unsigned int*)(g),
        (__attribute__((address_space(3))) unsigned int*)(l), 16, 0, 0);
}

// Quad-exchange for P->A-fragment redistribution (in-register, no LDS).
#if __has_builtin(__builtin_amdgcn_permlane32_swap) && __has_builtin(__builtin_amdgcn_permlane16_swap)
__device__ __forceinline__ void quad_swap(unsigned A, unsigned B, unsigned& dlo,
                                          unsigned& dhi, int quad) {
    auto t = __builtin_amdgcn_permlane32_swap(A, B, false, false);   // [A0,A1,B0,B1],[A2,A3,B2,B3]
    auto u = __builtin_amdgcn_permlane16_swap(t[0], t[1], false, false);
    dlo = u[0];  // [A0,A2,B0,B2]
    dhi = u[1];  // [A1,A3,B1,B3]
}
#else
__device__ __forceinline__ void quad_swap(unsigned A, unsigned B, unsigned& dlo,
                                          unsigned& dhi, int quad) {
    unsigned As = (unsigned)__shfl_xor((int)A, 32, 64);
    unsigned Bs = (unsigned)__shfl_xor((int)B, 32, 64);
    unsigned tx = (quad < 2) ? A : Bs;   // [A0,A1,B0,B1]
    unsigned ty = (quad < 2) ? As : B;   // [A2,A3,B2,B3]
    unsigned txs = (unsigned)__shfl_xor((int)tx, 16, 64);
    unsigned tys = (unsigned)__shfl_xor((int)ty, 16, 64);
    dlo = ((quad & 1) == 0) ? tx : tys;
    dhi = ((quad & 1) == 0) ? txs : ty;
}
#endif

// ---------------- fused cast fp32 -> bf16 for all 7 inputs ----------------
__global__ __launch_bounds__(256) void cast_all(
    const float* __restrict__ q, const float* __restrict__ k, const float* __restrict__ v,
    const float* __restrict__ wq, const float* __restrict__ wk, const float* __restrict__ wv,
    const float* __restrict__ wo, u16* __restrict__ dst) {
    int i = blockIdx.x * 256 + threadIdx.x;  // float4 index, grid covers 4194304 exactly
    const float* src;
    int off;
    if (i < 3145728) {
        int seg = i >> 20;
        src = (seg == 0) ? q : (seg == 1) ? k : v;
        off = i - (seg << 20);
    } else {
        int j = (i - 3145728) >> 18;
        src = (j == 0) ? wq : (j == 1) ? wk : (j == 2) ? wv : wo;
        off = (i - 3145728) - (j << 18);
    }
    float4 val = ((const float4*)src)[off];
    u16x4 o4;
    o4.x = f2bf(val.x); o4.y = f2bf(val.y); o4.z = f2bf(val.z); o4.w = f2bf(val.w);
    ((u16x4*)dst)[i] = o4;
}

// ---------------- fused QKV projection GEMM v4 (round-6/8/9 proven): 256x128, 8 waves ----------------
// TOOLCHAIN RULE (established r3-r7): VGPR cap = 65536/block_threads (256->256, 512->128,
// 1024->64); NO __launch_bounds__ hint moves it ((512,2) and (512,1) both left 128 and
// spilled 399 MB). Per-wave footprint must fit BY CONSTRUCTION. 512 thr = 8 waves
// (4M x 2N), 64x64 out/wave -> 96 VGPR measured < 128. 256M x 128N tile, BK=64,
// double-buffered 96 KB LDS, 2-tile-deep prefetch, counted vmcnt(6) (never 0 mid-loop),
// raw s_barrier, setprio. Measured ~47 us, no spill.
__global__ __launch_bounds__(512) void qkv_gemm(
    const u16* __restrict__ Xq, const u16* __restrict__ Xk, const u16* __restrict__ Xv,
    const u16* __restrict__ Wq, const u16* __restrict__ Wk, const u16* __restrict__ Wv,
    u16* __restrict__ Qo, u16* __restrict__ Ko, u16* __restrict__ Vto) {
    constexpr int K = 1024;
    const int blk = blockIdx.x;     // ((z*8+nb)<<4) | mb
    const int mb = blk & 15;
    const int g = blk >> 4;
    const int z = g >> 3;
    const int nb = g & 7;
    const u16* __restrict__ A = (z == 0) ? Xq : (z == 1) ? Xk : Xv;
    const u16* __restrict__ W = (z == 0) ? Wq : (z == 1) ? Wk : Wv;
    u16* __restrict__ Out = (z == 0) ? Qo : (z == 1) ? Ko : Vto;

    __shared__ __align__(16) u16 Asm[2 * 256 * 64];  // 64 KB (double-buffered A tile)
    __shared__ __align__(16) u16 Bsm[2 * 128 * 64];  // 32 KB (double-buffered B tile)

    const int t = threadIdx.x;
    const int lane = t & 63, wave = t >> 6;
    const int quad = lane >> 4, c = lane & 15, cx = c & 7;
    const int wm = wave >> 1, wn = wave & 1;   // 4 x 2 wave grid, 64x64 out each
    const int rowA0 = mb * 256;
    const int colB0 = nb * 128;

    const int l3 = lane >> 3, l7 = lane & 7;
    const int chs = (l7 ^ l3) << 3;
    const u16* gA[4];
    const u16* gB[2];
    int lbA[4];
    int lbB[2];
#pragma unroll
    for (int i = 0; i < 4; ++i) {
        int row = wave * 32 + i * 8 + l3;
        gA[i] = A + (size_t)(rowA0 + row) * K + chs;
        lbA[i] = (wave * 32 + i * 8) * 64;
    }
#pragma unroll
    for (int i = 0; i < 2; ++i) {
        int row = wave * 16 + i * 8 + l3;
        gB[i] = W + (size_t)(colB0 + row) * K + chs;
        lbB[i] = (wave * 16 + i * 8) * 64;
    }

    const f32x4 zero4 = {0.f, 0.f, 0.f, 0.f};
    f32x4 acc[4][4];
#pragma unroll
    for (int i = 0; i < 4; ++i)
#pragma unroll
        for (int j = 0; j < 4; ++j) acc[i][j] = zero4;

    // prologue: stage tiles 0 and 1 (6 loads each), wait tile 0 only
#pragma unroll
    for (int i = 0; i < 4; ++i) gload16(gA[i], Asm + lbA[i]);
#pragma unroll
    for (int i = 0; i < 2; ++i) gload16(gB[i], Bsm + lbB[i]);
#pragma unroll
    for (int i = 0; i < 4; ++i) gload16(gA[i] + 64, Asm + 16384 + lbA[i]);
#pragma unroll
    for (int i = 0; i < 2; ++i) gload16(gB[i] + 64, Bsm + 8192 + lbB[i]);
    asm volatile("s_waitcnt vmcnt(6)" ::: "memory");
    __builtin_amdgcn_s_barrier();
    asm volatile("" ::: "memory");

    for (int kt = 0; kt < 16; ++kt) {
        const int cur = kt & 1;
        const u16* Ab = Asm + cur * 16384;
        const u16* Bb = Bsm + cur * 8192;
#pragma unroll
        for (int ks = 0; ks < 2; ++ks) {
            const int co = ((ks * 4 + quad) ^ cx) << 3;
            bf16x8 af[4], bfr[4];
#pragma unroll
            for (int mi = 0; mi < 4; ++mi)
                af[mi] = *(const bf16x8*)(Ab + (wm * 64 + mi * 16 + c) * 64 + co);
#pragma unroll
            for (int nj = 0; nj < 4; ++nj)
                bfr[nj] = *(const bf16x8*)(Bb + (wn * 64 + nj * 16 + c) * 64 + co);
            if (ks == 1) {
                // all waves' reads of buf[cur] landed; sync, then refill the freed buffer
                asm volatile("s_waitcnt lgkmcnt(0)" ::: "memory");
                __builtin_amdgcn_s_barrier();
                asm volatile("" ::: "memory");
                if (kt + 2 < 16) {
                    const int koff = (kt + 2) * 64;
                    u16* ab = Asm + cur * 16384;
                    u16* bb = Bsm + cur * 8192;
#pragma unroll
                    for (int i = 0; i < 4; ++i) gload16(gA[i] + koff, ab + lbA[i]);
#pragma unroll
                    for (int i = 0; i < 2; ++i) gload16(gB[i] + koff, bb + lbB[i]);
                }
            }
            __builtin_amdgcn_s_setprio(1);
            if (z == 2) {
#pragma unroll
                for (int mi = 0; mi < 4; ++mi)
#pragma unroll
                    for (int nj = 0; nj < 4; ++nj)
                        acc[mi][nj] = __builtin_amdgcn_mfma_f32_16x16x32_bf16(bfr[nj], af[mi], acc[mi][nj], 0, 0, 0);
            } else {
#pragma unroll
                for (int mi = 0; mi < 4; ++mi)
#pragma unroll
                    for (int nj = 0; nj < 4; ++nj)
                        acc[mi][nj] = __builtin_amdgcn_mfma_f32_16x16x32_bf16(af[mi], bfr[nj], acc[mi][nj], 0, 0, 0);
            }
            __builtin_amdgcn_s_setprio(0);
        }
        // tile kt+1 complete (kt+2's 6 loads remain outstanding); counted, never 0 mid-loop
        if (kt <= 13) {
            asm volatile("s_waitcnt vmcnt(6)" ::: "memory");
        } else {
            asm volatile("s_waitcnt vmcnt(0)" ::: "memory");
        }
        __builtin_amdgcn_s_barrier();
        asm volatile("" ::: "memory");
    }

    // 0.125 * log2(e): scores later exponentiate via exp2
    const float scale = (z == 0) ? 0.18033688011112042f : 1.0f;
#pragma unroll
    for (int mi = 0; mi < 4; ++mi) {
#pragma unroll
        for (int nj = 0; nj < 4; ++nj) {
#pragma unroll
            for (int r = 0; r < 4; ++r) {
                float v = acc[mi][nj][r];
                if (z == 2) {
                    int n = colB0 + wn * 64 + nj * 16 + quad * 4 + r;  // feature (h*64+d)
                    int m = rowA0 + wm * 64 + mi * 16 + c;             // token (b*2048+s)
                    int b = m >> 11, s = m & 2047, h = n >> 6, d = n & 63;
                    Out[((((b << 4) | h) << 6) + d) * 2048 + s] = f2bf(v);
                } else {
                    int m = rowA0 + wm * 64 + mi * 16 + quad * 4 + r;  // token
                    int n = colB0 + wn * 64 + nj * 16 + c;             // feature
                    int b = m >> 11, s = m & 2047, h = n >> 6, d = n & 63;
                    Out[((((b << 4) | h) * 2048 + s) << 6) + d] = f2bf(v * scale);
                }
            }
        }
    }
}

// ---------------- output projection GEMM v2 (round-9 proven): 128x128 pipelined ----------------
// Clones the qkv-v4 schedule sized under the register rule: 128M x 128N tile, 512 thr =
// 8 waves (2M x 4N), 64x32 out/wave -> acc[4][2]=32 VGPR (~80 total < 128 cap). Double-
// buffered 64 KB LDS, 2-tile-deep prefetch, counted vmcnt(4) (never 0 mid-loop), raw
// s_barrier, setprio. Grid 32mb x 8nb = 256 blocks = exactly 1/CU.
__global__ __launch_bounds__(512) void out_gemm(const u16* __restrict__ A,
                                                const u16* __restrict__ W,
                                                float* __restrict__ Out) {
    constexpr int K = 1024;
    __shared__ __align__(16) u16 Asm[2 * 128 * 64];  // 32 KB
    __shared__ __align__(16) u16 Bsm[2 * 128 * 64];  // 32 KB
    const int blk = blockIdx.x;  // nb*32 + mb  => blk%8 == mb%8 (W-panel shared per XCD)
    const int mb = blk & 31;
    const int nb = blk >> 5;
    const int t = threadIdx.x;
    const int lane = t & 63, wave = t >> 6;
    const int quad = lane >> 4, c = lane & 15, cx = c & 7;
    const int wm = wave >> 2, wn = wave & 3;  // 2 x 4 wave grid, 64x32 out each
    const int rowA0 = mb * 128;
    const int colB0 = nb * 128;

    const int l3 = lane >> 3, l7 = lane & 7;
    const int chs = (l7 ^ l3) << 3;
    const u16* gA[2];
    const u16* gB[2];
    int lb[2];
#pragma unroll
    for (int i = 0; i < 2; ++i) {
        int row = wave * 16 + i * 8 + l3;
        gA[i] = A + (size_t)(rowA0 + row) * K + chs;
        gB[i] = W + (size_t)(colB0 + row) * K + chs;
        lb[i] = (wave * 16 + i * 8) * 64;
    }

    const f32x4 zero4 = {0.f, 0.f, 0.f, 0.f};
    f32x4 acc[4][2];
#pragma unroll
    for (int i = 0; i < 4; ++i)
#pragma unroll
        for (int j = 0; j < 2; ++j) acc[i][j] = zero4;

    // prologue: stage tiles 0 and 1 (4 loads each), wait tile 0 only
#pragma unroll
    for (int i = 0; i < 2; ++i) {
        gload16(gA[i], Asm + lb[i]);
        gload16(gB[i], Bsm + lb[i]);
    }
#pragma unroll
    for (int i = 0; i < 2; ++i) {
        gload16(gA[i] + 64, Asm + 8192 + lb[i]);
        gload16(gB[i] + 64, Bsm + 8192 + lb[i]);
    }
    asm volatile("s_waitcnt vmcnt(4)" ::: "memory");
    __builtin_amdgcn_s_barrier();
    asm volatile("" ::: "memory");

    for (int kt = 0; kt < 16; ++kt) {
        const int cur = kt & 1;
        const u16* Ab = Asm + cur * 8192;
        const u16* Bb = Bsm + cur * 8192;
#pragma unroll
        for (int ks = 0; ks < 2; ++ks) {
            const int co = ((ks * 4 + quad) ^ cx) << 3;
            bf16x8 af[4], bfr[2];
#pragma unroll
            for (int mi = 0; mi < 4; ++mi)
                af[mi] = *(const bf16x8*)(Ab + (wm * 64 + mi * 16 + c) * 64 + co);
#pragma unroll
            for (int nj = 0; nj < 2; ++nj)
                bfr[nj] = *(const bf16x8*)(Bb + (wn * 32 + nj * 16 + c) * 64 + co);
            if (ks == 1) {
                asm volatile("s_waitcnt lgkmcnt(0)" ::: "memory");
                __builtin_amdgcn_s_barrier();
                asm volatile("" ::: "memory");
                if (kt + 2 < 16) {
                    const int koff = (kt + 2) * 64;
                    u16* ab = Asm + cur * 8192;
                    u16* bb = Bsm + cur * 8192;
#pragma unroll
                    for (int i = 0; i < 2; ++i) {
                        gload16(gA[i] + koff, ab + lb[i]);
                        gload16(gB[i] + koff, bb + lb[i]);
                    }
                }
            }
            __builtin_amdgcn_s_setprio(1);
#pragma unroll
            for (int mi = 0; mi < 4; ++mi)
#pragma unroll
                for (int nj = 0; nj < 2; ++nj)
                    acc[mi][nj] = __builtin_amdgcn_mfma_f32_16x16x32_bf16(af[mi], bfr[nj], acc[mi][nj], 0, 0, 0);
            __builtin_amdgcn_s_setprio(0);
        }
        // tile kt+1 complete (kt+2's 4 loads remain outstanding); counted, never 0 mid-loop
        if (kt <= 13) {
            asm volatile("s_waitcnt vmcnt(4)" ::: "memory");
        } else {
            asm volatile("s_waitcnt vmcnt(0)" ::: "memory");
        }
        __builtin_amdgcn_s_barrier();
        asm volatile("" ::: "memory");
    }

#pragma unroll
    for (int mi = 0; mi < 4; ++mi)
#pragma unroll
        for (int nj = 0; nj < 2; ++nj)
#pragma unroll
            for (int r = 0; r < 4; ++r) {
                int m = rowA0 + wm * 64 + mi * 16 + quad * 4 + r;
                int n = colB0 + wn * 32 + nj * 16 + c;
                Out[(m << 10) + n] = acc[mi][nj][r];
            }
}

// ---------------- flash attention v9 (round-8 proven): split-K + cvt_pk + setprio ----------------
__global__ __launch_bounds__(512, 4) void flash_attn(const u16* __restrict__ Qp,
                                                     const u16* __restrict__ Kp,
                                                     const u16* __restrict__ Vt,
                                                     u16* __restrict__ Ob) {
    constexpr int S = 2048;
    const int blk = blockIdx.x;
    const int j = blk & 31;
    const int bh = ((j & 7) << 2) | (j >> 3);
    const int b = bh >> 4, h = bh & 15;
    const int t = threadIdx.x, wave = t >> 6, lane = t & 63;
    const int wq = wave & 3, kh = wave >> 2;
    const int quad = lane >> 4, c = lane & 15, cx = c & 7;
    const int qw = (blk >> 5) * 128 + wq * 32;
    const u16* Qb = Qp + (bh * S + qw) * 64;
    const u16* Kb = Kp + (bh * S + kh * 1024) * 64;
    const u16* Vb = Vt + bh * 64 * S + kh * 1024;  // V^T [dim][key]

    // 64 KB: K tiles [kh][buf] at smem[0..16384), V tiles at smem[16384..32768)
    __shared__ __align__(16) u16 smem[32768];
    u16* const Kh = smem + kh * 8192;          // this half's two K buffers
    u16* const Vh = smem + 16384 + kh * 8192;  // this half's two V buffers

    // Q fragments (B-operand): lane c holds Q[q=qt*16+c][dim=hf*32+quad*8+j]
    bf16x8 qf[2][2];
#pragma unroll
    for (int qt = 0; qt < 2; ++qt)
#pragma unroll
        for (int hf = 0; hf < 2; ++hf)
            qf[qt][hf] = *(const bf16x8*)(Qb + (qt * 16 + c) * 64 + hf * 32 + quad * 8);

    // all-ones bf16 B fragment for denominator MFMAs
    u16x8 ou;
#pragma unroll
    for (int i = 0; i < 8; ++i) ou[i] = 0x3F80;
    const bf16x8 onesf = __builtin_bit_cast(bf16x8, ou);

    // staging: within a kh-group, wave wq instr i covers physical chunks [wq*128+i*64, +64)
    const int l3 = lane >> 3, l7 = lane & 7;
    const int chs = (l7 ^ l3) << 3;
    const u16* gK[2];
    const u16* gV[2];
    int lbase[2];
#pragma unroll
    for (int i = 0; i < 2; ++i) {
        int row = wq * 16 + i * 8 + l3;
        gK[i] = Kb + row * 64 + chs;    // += it*4096 per tile
        gV[i] = Vb + row * 2048 + chs;  // += it*64 per tile
        lbase[i] = (wq * 128 + i * 64) * 8;
    }
    // preload tile 0 of this half
#pragma unroll
    for (int i = 0; i < 2; ++i) {
        gload16(gK[i], Kh + lbase[i]);
        gload16(gV[i], Vh + lbase[i]);
    }
    __syncthreads();

    const f32x4 zero4 = {0.f, 0.f, 0.f, 0.f};
    f32x4 o[2][4];
    f32x4 ol[2];  // denominator: row-sum of P (register-aligned with o)
#pragma unroll
    for (int qt = 0; qt < 2; ++qt) {
        ol[qt] = zero4;
#pragma unroll
        for (int t2 = 0; t2 < 4; ++t2) o[qt][t2] = zero4;
    }

    const int co0 = (quad ^ cx) << 3, co1 = ((4 + quad) ^ cx) << 3;

    for (int it = 0; it < 16; ++it) {
        const int cur = it & 1;
        // prefetch next tile of this half into the other buffer
        if (it + 1 < 16) {
#pragma unroll
            for (int i = 0; i < 2; ++i) {
                gload16(gK[i] + (it + 1) * 4096, Kh + (cur ^ 1) * 4096 + lbase[i]);
                gload16(gV[i] + (it + 1) * 64, Vh + (cur ^ 1) * 4096 + lbase[i]);
            }
        }
        const u16* Kc = Kh + cur * 4096;
        const u16* Vc = Vh + cur * 4096;
        // ---- transposed scores: Sc^T[key][q] = K_tile * Q^T ----
        f32x4 sc[4][2];
        __builtin_amdgcn_s_setprio(1);
#pragma unroll
        for (int kt = 0; kt < 4; ++kt) {
            const int krow = (kt * 16 + c) * 64;
            bf16x8 kf0 = *(const bf16x8*)(Kc + krow + co0);
            bf16x8 kf1 = *(const bf16x8*)(Kc + krow + co1);
#pragma unroll
            for (int qt = 0; qt < 2; ++qt) {
                f32x4 zz = zero4;
                zz = __builtin_amdgcn_mfma_f32_16x16x32_bf16(kf0, qf[qt][0], zz, 0, 0, 0);
                zz = __builtin_amdgcn_mfma_f32_16x16x32_bf16(kf1, qf[qt][1], zz, 0, 0, 0);
                sc[kt][qt] = zz;
            }
        }
        __builtin_amdgcn_s_setprio(0);
        // ---- exp2 + cvt_pk + in-register quad-swap to A-fragment layout ----
        bf16x8 af[2][2];
#pragma unroll
        for (int qt = 0; qt < 2; ++qt) {
            unsigned dw[4][2];
#pragma unroll
            for (int kt = 0; kt < 4; ++kt) {
                dw[kt][0] = cvtpk(EXP2(sc[kt][qt][0]), EXP2(sc[kt][qt][1]));
                dw[kt][1] = cvtpk(EXP2(sc[kt][qt][2]), EXP2(sc[kt][qt][3]));
            }
#pragma unroll
            for (int hh = 0; hh < 2; ++hh) {
                unsigned d0, d1, d2, d3;
                quad_swap(dw[2 * hh][0], dw[2 * hh + 1][0], d0, d2, quad);
                quad_swap(dw[2 * hh][1], dw[2 * hh + 1][1], d1, d3, quad);
                ui32x4 dd = {d0, d1, d2, d3};
                af[qt][hh] = __builtin_bit_cast(bf16x8, dd);
            }
        }
        // ---- O += P*V, l += P*ones (P entirely in registers) ----
        __builtin_amdgcn_s_setprio(1);
#pragma unroll
        for (int qt = 0; qt < 2; ++qt) {
            ol[qt] = __builtin_amdgcn_mfma_f32_16x16x32_bf16(af[qt][0], onesf, ol[qt], 0, 0, 0);
            ol[qt] = __builtin_amdgcn_mfma_f32_16x16x32_bf16(af[qt][1], onesf, ol[qt], 0, 0, 0);
        }
#pragma unroll
        for (int t2 = 0; t2 < 4; ++t2) {
            const int vrow = (t2 * 16 + c) * 64;
            bf16x8 vf0 = *(const bf16x8*)(Vc + vrow + co0);
            bf16x8 vf1 = *(const bf16x8*)(Vc + vrow + co1);
#pragma unroll
            for (int qt = 0; qt < 2; ++qt) {
                o[qt][t2] = __builtin_amdgcn_mfma_f32_16x16x32_bf16(af[qt][0], vf0, o[qt][t2], 0, 0, 0);
                o[qt][t2] = __builtin_amdgcn_mfma_f32_16x16x32_bf16(af[qt][1], vf1, o[qt][t2], 0, 0, 0);
            }
        }
        __builtin_amdgcn_s_setprio(0);
        __syncthreads();  // buffer lifecycle + drains prefetch vmcnt
    }
    // ---- combine halves through LDS (tiles dead after final barrier above) ----
    // per (wq,lane): 41-dword padded slot (41 mod 32 = 9, coprime -> conflict-free)
    float* const cb = ((float*)smem) + ((wq << 6) | lane) * 41;
    if (kh == 1) {
        int idx = 0;
#pragma unroll
        for (int qt = 0; qt < 2; ++qt)
#pragma unroll
            for (int t2 = 0; t2 < 4; ++t2)
#pragma unroll
                for (int r = 0; r < 4; ++r) cb[idx++] = o[qt][t2][r];
#pragma unroll
        for (int qt = 0; qt < 2; ++qt)
#pragma unroll
            for (int r = 0; r < 4; ++r) cb[idx++] = ol[qt][r];
    }
    __syncthreads();
    if (kh == 0) {
        int idx = 0;
#pragma unroll
        for (int qt = 0; qt < 2; ++qt)
#pragma unroll
            for (int t2 = 0; t2 < 4; ++t2)
#pragma unroll
                for (int r = 0; r < 4; ++r) o[qt][t2][r] += cb[idx++];
#pragma unroll
        for (int qt = 0; qt < 2; ++qt)
#pragma unroll
            for (int r = 0; r < 4; ++r) ol[qt][r] += cb[idx++];
        // ---- epilogue: normalize and store [B,S,H,D] ----
#pragma unroll
        for (int qt = 0; qt < 2; ++qt)
#pragma unroll
            for (int r = 0; r < 4; ++r) {
                float inv = 1.f / ol[qt][r];
                int row = qw + qt * 16 + quad * 4 + r;
                int base = ((b * S + row) * 16 + h) * 64;
#pragma unroll
                for (int t2 = 0; t2 < 4; ++t2)
                    Ob[base + t2 * 16 + c] = f2bf(o[qt][t2][r] * inv);
            }
    }
}

extern "C" void kernel_launch(void* const* d_in, const int* in_sizes, int n_in,
                              void* d_out, int out_size, void* d_ws, size_t ws_size,
                              hipStream_t stream) {
    const float* q  = (const float*)d_in[0];
    const float* k  = (const float*)d_in[1];
    const float* v  = (const float*)d_in[2];
    const float* wq = (const float*)d_in[3];
    const float* wk = (const float*)d_in[4];
    const float* wv = (const float*)d_in[5];
    const float* wo = (const float*)d_in[6];

    u16* ws = (u16*)d_ws;
    u16* qb  = ws;              // 4194304 elems
    u16* kb  = ws + 4194304;
    u16* vb  = ws + 8388608;
    u16* wqb = ws + 12582912;   // 1048576 elems each
    u16* wkb = ws + 13631488;
    u16* wvb = ws + 14680064;
    u16* wob = ws + 15728640;
    u16* Qp  = ws + 16777216;   // [B,H,S,D]
    u16* Kp  = ws + 20971520;   // [B,H,S,D]
    u16* Vtp = ws + 25165824;   // [B,H,D,S]
    u16* Obf = ws + 29360128;   // [B,S,H,D]

    cast_all<<<16384, 256, 0, stream>>>(q, k, v, wq, wk, wv, wo, ws);

    // fused QKV projections: 1-D grid 384 x 512 threads, 256x128 pipelined tiles
    qkv_gemm<<<384, 512, 0, stream>>>(qb, kb, vb, wqb, wkb, wvb, Qp, Kp, Vtp);

    // flash attention: 1-D grid 512 x 512 threads, in-block split-K
    flash_attn<<<512, 512, 0, stream>>>(Qp, Kp, Vtp, Obf);

    // output projection v2: 1-D grid 256 x 512 threads, 128x128 pipelined tiles
    out_gemm<<<256, 512, 0, stream>>>(Obf, wob, (float*)d_out);
}

// Round 12
// 201.738 us; speedup vs baseline: 1.0268x; 1.0268x over previous
//
#include <hip/hip_runtime.h>
#include <hip/hip_bf16.h>
#include <math.h>

typedef float f32x4 __attribute__((ext_vector_type(4)));
typedef __bf16 bf16x8 __attribute__((ext_vector_type(8)));
typedef unsigned short u16;
typedef u16 u16x8 __attribute__((ext_vector_type(8)));
typedef u16 u16x4 __attribute__((ext_vector_type(4)));
typedef unsigned ui32x4 __attribute__((ext_vector_type(4)));

// round-to-nearest-even fp32 -> bf16
__device__ __forceinline__ u16 f2bf(float f) {
    unsigned u = __builtin_bit_cast(unsigned, f);
    u = (u + 0x7fffu + ((u >> 16) & 1u)) >> 16;
    return (u16)u;
}
// pack two fp32 -> two bf16 (RNE) in ONE VALU op (no builtin on gfx950 - inline asm)
__device__ __forceinline__ unsigned cvtpk(float a, float b) {
    unsigned r;
    asm("v_cvt_pk_bf16_f32 %0, %1, %2" : "=v"(r) : "v"(a), "v"(b));
    return r;
}

#if __has_builtin(__builtin_amdgcn_exp2f)
#define EXP2(x) __builtin_amdgcn_exp2f(x)
#else
#define EXP2(x) exp2f(x)
#endif

// async global->LDS 16B/lane: LDS dest = wave-uniform base + lane*16
__device__ __forceinline__ void gload16(const u16* g, u16* l) {
    __builtin_amdgcn_global_load_lds(
        (const __attribute__((address_space(1))) unsigned int*)(g),
        (__attribute__((address_space(3))) unsigned int*)(l), 16, 0, 0);
}

// Quad-exchange for P->A-fragment redistribution (in-register, no LDS).
#if __has_builtin(__builtin_amdgcn_permlane32_swap) && __has_builtin(__builtin_amdgcn_permlane16_swap)
__device__ __forceinline__ void quad_swap(unsigned A, unsigned B, unsigned& dlo,
                                          unsigned& dhi, int quad) {
    auto t = __builtin_amdgcn_permlane32_swap(A, B, false, false);   // [A0,A1,B0,B1],[A2,A3,B2,B3]
    auto u = __builtin_amdgcn_permlane16_swap(t[0], t[1], false, false);
    dlo = u[0];  // [A0,A2,B0,B2]
    dhi = u[1];  // [A1,A3,B1,B3]
}
#else
__device__ __forceinline__ void quad_swap(unsigned A, unsigned B, unsigned& dlo,
                                          unsigned& dhi, int quad) {
    unsigned As = (unsigned)__shfl_xor((int)A, 32, 64);
    unsigned Bs = (unsigned)__shfl_xor((int)B, 32, 64);
    unsigned tx = (quad < 2) ? A : Bs;   // [A0,A1,B0,B1]
    unsigned ty = (quad < 2) ? As : B;   // [A2,A3,B2,B3]
    unsigned txs = (unsigned)__shfl_xor((int)tx, 16, 64);
    unsigned tys = (unsigned)__shfl_xor((int)ty, 16, 64);
    dlo = ((quad & 1) == 0) ? tx : tys;
    dhi = ((quad & 1) == 0) ? txs : ty;
}
#endif

// ---------------- fused cast fp32 -> bf16 for all 7 inputs ----------------
__global__ __launch_bounds__(256) void cast_all(
    const float* __restrict__ q, const float* __restrict__ k, const float* __restrict__ v,
    const float* __restrict__ wq, const float* __restrict__ wk, const float* __restrict__ wv,
    const float* __restrict__ wo, u16* __restrict__ dst) {
    int i = blockIdx.x * 256 + threadIdx.x;  // float4 index, grid covers 4194304 exactly
    const float* src;
    int off;
    if (i < 3145728) {
        int seg = i >> 20;
        src = (seg == 0) ? q : (seg == 1) ? k : v;
        off = i - (seg << 20);
    } else {
        int j = (i - 3145728) >> 18;
        src = (j == 0) ? wq : (j == 1) ? wk : (j == 2) ? wv : wo;
        off = (i - 3145728) - (j << 18);
    }
    float4 val = ((const float4*)src)[off];
    u16x4 o4;
    o4.x = f2bf(val.x); o4.y = f2bf(val.y); o4.z = f2bf(val.z); o4.w = f2bf(val.w);
    ((u16x4*)dst)[i] = o4;
}

// ---------------- fused QKV projection GEMM v5: 256x128, 80 KB LDS, tail-free ----------------
// Round-11 diagnosis: 96 KB LDS => 1 block/CU => capacity 256 < grid 384 => round 2 runs
// the machine half-idle (25-33% wall waste; Occupancy 14% vs 25% full). v5 cuts LDS to
// 80 KB by SINGLE-buffering the B tile (16 KB) while keeping A's 2-tile-deep prefetch:
// 2 blocks/CU => capacity 512 >= 384, all blocks co-resident, tail gone, 16 waves/CU.
// vmcnt derivation (retires oldest-first): per K-step issue B(kt+1) BEFORE A(kt+2), so
// end-of-step vmcnt(4) retires A(kt+1)+B(kt+1) and leaves exactly A(kt+2)x4 in flight.
// B's restage is protected by the existing lgkmcnt(0)+barrier (reads of B(kt) complete).
// TOOLCHAIN RULE (r3-r7): VGPR cap = 65536/block_threads; footprint 96 < 128 OK.
__global__ __launch_bounds__(512) void qkv_gemm(
    const u16* __restrict__ Xq, const u16* __restrict__ Xk, const u16* __restrict__ Xv,
    const u16* __restrict__ Wq, const u16* __restrict__ Wk, const u16* __restrict__ Wv,
    u16* __restrict__ Qo, u16* __restrict__ Ko, u16* __restrict__ Vto) {
    constexpr int K = 1024;
    const int blk = blockIdx.x;     // ((z*8+nb)<<4) | mb
    const int mb = blk & 15;
    const int g = blk >> 4;
    const int z = g >> 3;
    const int nb = g & 7;
    const u16* __restrict__ A = (z == 0) ? Xq : (z == 1) ? Xk : Xv;
    const u16* __restrict__ W = (z == 0) ? Wq : (z == 1) ? Wk : Wv;
    u16* __restrict__ Out = (z == 0) ? Qo : (z == 1) ? Ko : Vto;

    __shared__ __align__(16) u16 Asm[2 * 256 * 64];  // 64 KB (double-buffered A tile)
    __shared__ __align__(16) u16 Bsm[128 * 64];      // 16 KB (SINGLE-buffered B tile)

    const int t = threadIdx.x;
    const int lane = t & 63, wave = t >> 6;
    const int quad = lane >> 4, c = lane & 15, cx = c & 7;
    const int wm = wave >> 1, wn = wave & 1;   // 4 x 2 wave grid, 64x64 out each
    const int rowA0 = mb * 256;
    const int colB0 = nb * 128;

    const int l3 = lane >> 3, l7 = lane & 7;
    const int chs = (l7 ^ l3) << 3;
    const u16* gA[4];
    const u16* gB[2];
    int lbA[4];
    int lbB[2];
#pragma unroll
    for (int i = 0; i < 4; ++i) {
        int row = wave * 32 + i * 8 + l3;
        gA[i] = A + (size_t)(rowA0 + row) * K + chs;
        lbA[i] = (wave * 32 + i * 8) * 64;
    }
#pragma unroll
    for (int i = 0; i < 2; ++i) {
        int row = wave * 16 + i * 8 + l3;
        gB[i] = W + (size_t)(colB0 + row) * K + chs;
        lbB[i] = (wave * 16 + i * 8) * 64;
    }

    const f32x4 zero4 = {0.f, 0.f, 0.f, 0.f};
    f32x4 acc[4][4];
#pragma unroll
    for (int i = 0; i < 4; ++i)
#pragma unroll
        for (int j = 0; j < 4; ++j) acc[i][j] = zero4;

    // prologue: issue B(0), A(0), A(1) in that order; vmcnt(4) retires B(0)+A(0),
    // leaves A(1)x4 in flight.
#pragma unroll
    for (int i = 0; i < 2; ++i) gload16(gB[i], Bsm + lbB[i]);
#pragma unroll
    for (int i = 0; i < 4; ++i) gload16(gA[i], Asm + lbA[i]);
#pragma unroll
    for (int i = 0; i < 4; ++i) gload16(gA[i] + 64, Asm + 16384 + lbA[i]);
    asm volatile("s_waitcnt vmcnt(4)" ::: "memory");
    __builtin_amdgcn_s_barrier();
    asm volatile("" ::: "memory");

    for (int kt = 0; kt < 16; ++kt) {
        const int cur = kt & 1;
        const u16* Ab = Asm + cur * 16384;
        const u16* Bb = Bsm;
#pragma unroll
        for (int ks = 0; ks < 2; ++ks) {
            const int co = ((ks * 4 + quad) ^ cx) << 3;
            bf16x8 af[4], bfr[4];
#pragma unroll
            for (int mi = 0; mi < 4; ++mi)
                af[mi] = *(const bf16x8*)(Ab + (wm * 64 + mi * 16 + c) * 64 + co);
#pragma unroll
            for (int nj = 0; nj < 4; ++nj)
                bfr[nj] = *(const bf16x8*)(Bb + (wn * 64 + nj * 16 + c) * 64 + co);
            if (ks == 1) {
                // all waves' reads of A[cur] and B landed; sync, then refill both
                asm volatile("s_waitcnt lgkmcnt(0)" ::: "memory");
                __builtin_amdgcn_s_barrier();
                asm volatile("" ::: "memory");
                // B(kt+1) FIRST, then A(kt+2): vmcnt(4) at step end then retires
                // A(kt+1)+B(kt+1), leaving only A(kt+2)x4 outstanding.
                if (kt + 1 < 16) {
#pragma unroll
                    for (int i = 0; i < 2; ++i) gload16(gB[i] + (kt + 1) * 64, Bsm + lbB[i]);
                }
                if (kt + 2 < 16) {
                    const int koff = (kt + 2) * 64;
                    u16* ab = Asm + cur * 16384;
#pragma unroll
                    for (int i = 0; i < 4; ++i) gload16(gA[i] + koff, ab + lbA[i]);
                }
            }
            __builtin_amdgcn_s_setprio(1);
            if (z == 2) {
#pragma unroll
                for (int mi = 0; mi < 4; ++mi)
#pragma unroll
                    for (int nj = 0; nj < 4; ++nj)
                        acc[mi][nj] = __builtin_amdgcn_mfma_f32_16x16x32_bf16(bfr[nj], af[mi], acc[mi][nj], 0, 0, 0);
            } else {
#pragma unroll
                for (int mi = 0; mi < 4; ++mi)
#pragma unroll
                    for (int nj = 0; nj < 4; ++nj)
                        acc[mi][nj] = __builtin_amdgcn_mfma_f32_16x16x32_bf16(af[mi], bfr[nj], acc[mi][nj], 0, 0, 0);
            }
            __builtin_amdgcn_s_setprio(0);
        }
        // A(kt+1)+B(kt+1) landed (A(kt+2)x4 stays in flight); counted, never 0 mid-loop
        if (kt <= 13) {
            asm volatile("s_waitcnt vmcnt(4)" ::: "memory");
        } else {
            asm volatile("s_waitcnt vmcnt(0)" ::: "memory");
        }
        __builtin_amdgcn_s_barrier();
        asm volatile("" ::: "memory");
    }

    // 0.125 * log2(e): scores later exponentiate via exp2
    const float scale = (z == 0) ? 0.18033688011112042f : 1.0f;
#pragma unroll
    for (int mi = 0; mi < 4; ++mi) {
#pragma unroll
        for (int nj = 0; nj < 4; ++nj) {
#pragma unroll
            for (int r = 0; r < 4; ++r) {
                float v = acc[mi][nj][r];
                if (z == 2) {
                    int n = colB0 + wn * 64 + nj * 16 + quad * 4 + r;  // feature (h*64+d)
                    int m = rowA0 + wm * 64 + mi * 16 + c;             // token (b*2048+s)
                    int b = m >> 11, s = m & 2047, h = n >> 6, d = n & 63;
                    Out[((((b << 4) | h) << 6) + d) * 2048 + s] = f2bf(v);
                } else {
                    int m = rowA0 + wm * 64 + mi * 16 + quad * 4 + r;  // token
                    int n = colB0 + wn * 64 + nj * 16 + c;             // feature
                    int b = m >> 11, s = m & 2047, h = n >> 6, d = n & 63;
                    Out[((((b << 4) | h) * 2048 + s) << 6) + d] = f2bf(v * scale);
                }
            }
        }
    }
}

// ---------------- output projection GEMM v2 (round-9 proven): 128x128 pipelined ----------------
__global__ __launch_bounds__(512) void out_gemm(const u16* __restrict__ A,
                                                const u16* __restrict__ W,
                                                float* __restrict__ Out) {
    constexpr int K = 1024;
    __shared__ __align__(16) u16 Asm[2 * 128 * 64];  // 32 KB
    __shared__ __align__(16) u16 Bsm[2 * 128 * 64];  // 32 KB
    const int blk = blockIdx.x;  // nb*32 + mb  => blk%8 == mb%8 (W-panel shared per XCD)
    const int mb = blk & 31;
    const int nb = blk >> 5;
    const int t = threadIdx.x;
    const int lane = t & 63, wave = t >> 6;
    const int quad = lane >> 4, c = lane & 15, cx = c & 7;
    const int wm = wave >> 2, wn = wave & 3;  // 2 x 4 wave grid, 64x32 out each
    const int rowA0 = mb * 128;
    const int colB0 = nb * 128;

    const int l3 = lane >> 3, l7 = lane & 7;
    const int chs = (l7 ^ l3) << 3;
    const u16* gA[2];
    const u16* gB[2];
    int lb[2];
#pragma unroll
    for (int i = 0; i < 2; ++i) {
        int row = wave * 16 + i * 8 + l3;
        gA[i] = A + (size_t)(rowA0 + row) * K + chs;
        gB[i] = W + (size_t)(colB0 + row) * K + chs;
        lb[i] = (wave * 16 + i * 8) * 64;
    }

    const f32x4 zero4 = {0.f, 0.f, 0.f, 0.f};
    f32x4 acc[4][2];
#pragma unroll
    for (int i = 0; i < 4; ++i)
#pragma unroll
        for (int j = 0; j < 2; ++j) acc[i][j] = zero4;

    // prologue: stage tiles 0 and 1 (4 loads each), wait tile 0 only
#pragma unroll
    for (int i = 0; i < 2; ++i) {
        gload16(gA[i], Asm + lb[i]);
        gload16(gB[i], Bsm + lb[i]);
    }
#pragma unroll
    for (int i = 0; i < 2; ++i) {
        gload16(gA[i] + 64, Asm + 8192 + lb[i]);
        gload16(gB[i] + 64, Bsm + 8192 + lb[i]);
    }
    asm volatile("s_waitcnt vmcnt(4)" ::: "memory");
    __builtin_amdgcn_s_barrier();
    asm volatile("" ::: "memory");

    for (int kt = 0; kt < 16; ++kt) {
        const int cur = kt & 1;
        const u16* Ab = Asm + cur * 8192;
        const u16* Bb = Bsm + cur * 8192;
#pragma unroll
        for (int ks = 0; ks < 2; ++ks) {
            const int co = ((ks * 4 + quad) ^ cx) << 3;
            bf16x8 af[4], bfr[2];
#pragma unroll
            for (int mi = 0; mi < 4; ++mi)
                af[mi] = *(const bf16x8*)(Ab + (wm * 64 + mi * 16 + c) * 64 + co);
#pragma unroll
            for (int nj = 0; nj < 2; ++nj)
                bfr[nj] = *(const bf16x8*)(Bb + (wn * 32 + nj * 16 + c) * 64 + co);
            if (ks == 1) {
                asm volatile("s_waitcnt lgkmcnt(0)" ::: "memory");
                __builtin_amdgcn_s_barrier();
                asm volatile("" ::: "memory");
                if (kt + 2 < 16) {
                    const int koff = (kt + 2) * 64;
                    u16* ab = Asm + cur * 8192;
                    u16* bb = Bsm + cur * 8192;
#pragma unroll
                    for (int i = 0; i < 2; ++i) {
                        gload16(gA[i] + koff, ab + lb[i]);
                        gload16(gB[i] + koff, bb + lb[i]);
                    }
                }
            }
            __builtin_amdgcn_s_setprio(1);
#pragma unroll
            for (int mi = 0; mi < 4; ++mi)
#pragma unroll
                for (int nj = 0; nj < 2; ++nj)
                    acc[mi][nj] = __builtin_amdgcn_mfma_f32_16x16x32_bf16(af[mi], bfr[nj], acc[mi][nj], 0, 0, 0);
            __builtin_amdgcn_s_setprio(0);
        }
        // tile kt+1 complete (kt+2's 4 loads remain outstanding); counted, never 0 mid-loop
        if (kt <= 13) {
            asm volatile("s_waitcnt vmcnt(4)" ::: "memory");
        } else {
            asm volatile("s_waitcnt vmcnt(0)" ::: "memory");
        }
        __builtin_amdgcn_s_barrier();
        asm volatile("" ::: "memory");
    }

#pragma unroll
    for (int mi = 0; mi < 4; ++mi)
#pragma unroll
        for (int nj = 0; nj < 2; ++nj)
#pragma unroll
            for (int r = 0; r < 4; ++r) {
                int m = rowA0 + wm * 64 + mi * 16 + quad * 4 + r;
                int n = colB0 + wn * 32 + nj * 16 + c;
                Out[(m << 10) + n] = acc[mi][nj][r];
            }
}

// ---------------- flash attention v9 (round-8 proven): split-K + cvt_pk + setprio ----------------
__global__ __launch_bounds__(512, 4) void flash_attn(const u16* __restrict__ Qp,
                                                     const u16* __restrict__ Kp,
                                                     const u16* __restrict__ Vt,
                                                     u16* __restrict__ Ob) {
    constexpr int S = 2048;
    const int blk = blockIdx.x;
    const int j = blk & 31;
    const int bh = ((j & 7) << 2) | (j >> 3);
    const int b = bh >> 4, h = bh & 15;
    const int t = threadIdx.x, wave = t >> 6, lane = t & 63;
    const int wq = wave & 3, kh = wave >> 2;
    const int quad = lane >> 4, c = lane & 15, cx = c & 7;
    const int qw = (blk >> 5) * 128 + wq * 32;
    const u16* Qb = Qp + (bh * S + qw) * 64;
    const u16* Kb = Kp + (bh * S + kh * 1024) * 64;
    const u16* Vb = Vt + bh * 64 * S + kh * 1024;  // V^T [dim][key]

    // 64 KB: K tiles [kh][buf] at smem[0..16384), V tiles at smem[16384..32768)
    __shared__ __align__(16) u16 smem[32768];
    u16* const Kh = smem + kh * 8192;          // this half's two K buffers
    u16* const Vh = smem + 16384 + kh * 8192;  // this half's two V buffers

    // Q fragments (B-operand): lane c holds Q[q=qt*16+c][dim=hf*32+quad*8+j]
    bf16x8 qf[2][2];
#pragma unroll
    for (int qt = 0; qt < 2; ++qt)
#pragma unroll
        for (int hf = 0; hf < 2; ++hf)
            qf[qt][hf] = *(const bf16x8*)(Qb + (qt * 16 + c) * 64 + hf * 32 + quad * 8);

    // all-ones bf16 B fragment for denominator MFMAs
    u16x8 ou;
#pragma unroll
    for (int i = 0; i < 8; ++i) ou[i] = 0x3F80;
    const bf16x8 onesf = __builtin_bit_cast(bf16x8, ou);

    // staging: within a kh-group, wave wq instr i covers physical chunks [wq*128+i*64, +64)
    const int l3f = lane >> 3, l7f = lane & 7;
    const int chsf = (l7f ^ l3f) << 3;
    const u16* gK[2];
    const u16* gV[2];
    int lbase[2];
#pragma unroll
    for (int i = 0; i < 2; ++i) {
        int row = wq * 16 + i * 8 + l3f;
        gK[i] = Kb + row * 64 + chsf;    // += it*4096 per tile
        gV[i] = Vb + row * 2048 + chsf;  // += it*64 per tile
        lbase[i] = (wq * 128 + i * 64) * 8;
    }
    // preload tile 0 of this half
#pragma unroll
    for (int i = 0; i < 2; ++i) {
        gload16(gK[i], Kh + lbase[i]);
        gload16(gV[i], Vh + lbase[i]);
    }
    __syncthreads();

    const f32x4 zero4 = {0.f, 0.f, 0.f, 0.f};
    f32x4 o[2][4];
    f32x4 ol[2];  // denominator: row-sum of P (register-aligned with o)
#pragma unroll
    for (int qt = 0; qt < 2; ++qt) {
        ol[qt] = zero4;
#pragma unroll
        for (int t2 = 0; t2 < 4; ++t2) o[qt][t2] = zero4;
    }

    const int co0 = (quad ^ cx) << 3, co1 = ((4 + quad) ^ cx) << 3;

    for (int it = 0; it < 16; ++it) {
        const int cur = it & 1;
        // prefetch next tile of this half into the other buffer
        if (it + 1 < 16) {
#pragma unroll
            for (int i = 0; i < 2; ++i) {
                gload16(gK[i] + (it + 1) * 4096, Kh + (cur ^ 1) * 4096 + lbase[i]);
                gload16(gV[i] + (it + 1) * 64, Vh + (cur ^ 1) * 4096 + lbase[i]);
            }
        }
        const u16* Kc = Kh + cur * 4096;
        const u16* Vc = Vh + cur * 4096;
        // ---- transposed scores: Sc^T[key][q] = K_tile * Q^T ----
        f32x4 sc[4][2];
        __builtin_amdgcn_s_setprio(1);
#pragma unroll
        for (int kt = 0; kt < 4; ++kt) {
            const int krow = (kt * 16 + c) * 64;
            bf16x8 kf0 = *(const bf16x8*)(Kc + krow + co0);
            bf16x8 kf1 = *(const bf16x8*)(Kc + krow + co1);
#pragma unroll
            for (int qt = 0; qt < 2; ++qt) {
                f32x4 zz = zero4;
                zz = __builtin_amdgcn_mfma_f32_16x16x32_bf16(kf0, qf[qt][0], zz, 0, 0, 0);
                zz = __builtin_amdgcn_mfma_f32_16x16x32_bf16(kf1, qf[qt][1], zz, 0, 0, 0);
                sc[kt][qt] = zz;
            }
        }
        __builtin_amdgcn_s_setprio(0);
        // ---- exp2 + cvt_pk + in-register quad-swap to A-fragment layout ----
        bf16x8 af[2][2];
#pragma unroll
        for (int qt = 0; qt < 2; ++qt) {
            unsigned dw[4][2];
#pragma unroll
            for (int kt = 0; kt < 4; ++kt) {
                dw[kt][0] = cvtpk(EXP2(sc[kt][qt][0]), EXP2(sc[kt][qt][1]));
                dw[kt][1] = cvtpk(EXP2(sc[kt][qt][2]), EXP2(sc[kt][qt][3]));
            }
#pragma unroll
            for (int hh = 0; hh < 2; ++hh) {
                unsigned d0, d1, d2, d3;
                quad_swap(dw[2 * hh][0], dw[2 * hh + 1][0], d0, d2, quad);
                quad_swap(dw[2 * hh][1], dw[2 * hh + 1][1], d1, d3, quad);
                ui32x4 dd = {d0, d1, d2, d3};
                af[qt][hh] = __builtin_bit_cast(bf16x8, dd);
            }
        }
        // ---- O += P*V, l += P*ones (P entirely in registers) ----
        __builtin_amdgcn_s_setprio(1);
#pragma unroll
        for (int qt = 0; qt < 2; ++qt) {
            ol[qt] = __builtin_amdgcn_mfma_f32_16x16x32_bf16(af[qt][0], onesf, ol[qt], 0, 0, 0);
            ol[qt] = __builtin_amdgcn_mfma_f32_16x16x32_bf16(af[qt][1], onesf, ol[qt], 0, 0, 0);
        }
#pragma unroll
        for (int t2 = 0; t2 < 4; ++t2) {
            const int vrow = (t2 * 16 + c) * 64;
            bf16x8 vf0 = *(const bf16x8*)(Vc + vrow + co0);
            bf16x8 vf1 = *(const bf16x8*)(Vc + vrow + co1);
#pragma unroll
            for (int qt = 0; qt < 2; ++qt) {
                o[qt][t2] = __builtin_amdgcn_mfma_f32_16x16x32_bf16(af[qt][0], vf0, o[qt][t2], 0, 0, 0);
                o[qt][t2] = __builtin_amdgcn_mfma_f32_16x16x32_bf16(af[qt][1], vf1, o[qt][t2], 0, 0, 0);
            }
        }
        __builtin_amdgcn_s_setprio(0);
        __syncthreads();  // buffer lifecycle + drains prefetch vmcnt
    }
    // ---- combine halves through LDS (tiles dead after final barrier above) ----
    // per (wq,lane): 41-dword padded slot (41 mod 32 = 9, coprime -> conflict-free)
    float* const cb = ((float*)smem) + ((wq << 6) | lane) * 41;
    if (kh == 1) {
        int idx = 0;
#pragma unroll
        for (int qt = 0; qt < 2; ++qt)
#pragma unroll
            for (int t2 = 0; t2 < 4; ++t2)
#pragma unroll
                for (int r = 0; r < 4; ++r) cb[idx++] = o[qt][t2][r];
#pragma unroll
        for (int qt = 0; qt < 2; ++qt)
#pragma unroll
            for (int r = 0; r < 4; ++r) cb[idx++] = ol[qt][r];
    }
    __syncthreads();
    if (kh == 0) {
        int idx = 0;
#pragma unroll
        for (int qt = 0; qt < 2; ++qt)
#pragma unroll
            for (int t2 = 0; t2 < 4; ++t2)
#pragma unroll
                for (int r = 0; r < 4; ++r) o[qt][t2][r] += cb[idx++];
#pragma unroll
        for (int qt = 0; qt < 2; ++qt)
#pragma unroll
            for (int r = 0; r < 4; ++r) ol[qt][r] += cb[idx++];
        // ---- epilogue: normalize and store [B,S,H,D] ----
#pragma unroll
        for (int qt = 0; qt < 2; ++qt)
#pragma unroll
            for (int r = 0; r < 4; ++r) {
                float inv = 1.f / ol[qt][r];
                int row = qw + qt * 16 + quad * 4 + r;
                int base = ((b * S + row) * 16 + h) * 64;
#pragma unroll
                for (int t2 = 0; t2 < 4; ++t2)
                    Ob[base + t2 * 16 + c] = f2bf(o[qt][t2][r] * inv);
            }
    }
}

extern "C" void kernel_launch(void* const* d_in, const int* in_sizes, int n_in,
                              void* d_out, int out_size, void* d_ws, size_t ws_size,
                              hipStream_t stream) {
    const float* q  = (const float*)d_in[0];
    const float* k  = (const float*)d_in[1];
    const float* v  = (const float*)d_in[2];
    const float* wq = (const float*)d_in[3];
    const float* wk = (const float*)d_in[4];
    const float* wv = (const float*)d_in[5];
    const float* wo = (const float*)d_in[6];

    u16* ws = (u16*)d_ws;
    u16* qb  = ws;              // 4194304 elems
    u16* kb  = ws + 4194304;
    u16* vb  = ws + 8388608;
    u16* wqb = ws + 12582912;   // 1048576 elems each
    u16* wkb = ws + 13631488;
    u16* wvb = ws + 14680064;
    u16* wob = ws + 15728640;
    u16* Qp  = ws + 16777216;   // [B,H,S,D]
    u16* Kp  = ws + 20971520;   // [B,H,S,D]
    u16* Vtp = ws + 25165824;   // [B,H,D,S]
    u16* Obf = ws + 29360128;   // [B,S,H,D]

    cast_all<<<16384, 256, 0, stream>>>(q, k, v, wq, wk, wv, wo, ws);

    // fused QKV projections: 1-D grid 384 x 512 threads, 256x128 tiles, 80 KB LDS
    // (2 blocks/CU -> capacity 512 >= 384, tail-free)
    qkv_gemm<<<384, 512, 0, stream>>>(qb, kb, vb, wqb, wkb, wvb, Qp, Kp, Vtp);

    // flash attention: 1-D grid 512 x 512 threads, in-block split-K
    flash_attn<<<512, 512, 0, stream>>>(Qp, Kp, Vtp, Obf);

    // output projection v2: 1-D grid 256 x 512 threads, 128x128 pipelined tiles
    out_gemm<<<256, 512, 0, stream>>>(Obf, wob, (float*)d_out);
}